// Round 8
// baseline (128.733 us; speedup 1.0000x reference)
//
#include <hip/hip_runtime.h>

typedef unsigned short u16;
typedef unsigned int u32;
typedef float f32x4 __attribute__((ext_vector_type(4)));
typedef float f32x16 __attribute__((ext_vector_type(16)));
typedef _Float16 h16x8 __attribute__((ext_vector_type(8)));
typedef u32 u32x4 __attribute__((ext_vector_type(4)));
typedef u32 u32x2 __attribute__((ext_vector_type(2)));
typedef u16 u16x4 __attribute__((ext_vector_type(4)));

#define NB 8
#define CC 192
#define OO 96
#define NN 4096
#define NSPLIT 3
#define XPAD 200   // proj LDS row pad
#define LOG2E 1.4426950408889634f

static __device__ __forceinline__ u16 f2h(float f) {
  _Float16 h = (_Float16)f;
  return __builtin_bit_cast(u16, h);
}
// ret0 = [a.lanes0-31 | b.lanes0-31], ret1 = [a.lanes32-63 | b.lanes32-63]
static __device__ __forceinline__ void plane_swap(u32& a, u32& b) {
  u32x2 r = __builtin_amdgcn_permlane32_swap(a, b, false, false);
  a = r[0]; b = r[1];
}
static __device__ __forceinline__ float half_combine_max(float x) {
  u32 a = __builtin_bit_cast(u32, x), b = a;
  plane_swap(a, b);
  return fmaxf(__builtin_bit_cast(float, a), __builtin_bit_cast(float, b));
}
static __device__ __forceinline__ float half_combine_sum(float x) {
  u32 a = __builtin_bit_cast(u32, x), b = a;
  plane_swap(a, b);
  return __builtin_bit_cast(float, a) + __builtin_bit_cast(float, b);
}
static __device__ __forceinline__ float max3f(float a, float b, float c) {
  return fmaxf(fmaxf(a, b), c);   // clang fuses to v_max3_f32
}

// ---------------- Kernel 1: theta/phi/g projections as fp16 MFMA GEMMs ----------------
// Outputs in MFMA-fragment-preswizzled layouts (32x32x16 frags). Theta side is
// pre-scaled by log2(e) so attention can use native exp2.
__global__ __launch_bounds__(256) void proj_kernel(
    const float* __restrict__ x,
    const float* __restrict__ g_w, const float* __restrict__ g_b,
    const float* __restrict__ th_w, const float* __restrict__ th_b,
    const float* __restrict__ ph_w, const float* __restrict__ ph_b,
    u16* __restrict__ QB, u16* __restrict__ KA, u16* __restrict__ VA)
{
  __shared__ __align__(16) u16 Xs[64][XPAD];
  __shared__ __align__(16) u16 Ws[96][XPAD];
  const int b = blockIdx.y, n0 = blockIdx.x * 64, tid = threadIdx.x;
  const int lane = tid & 63, wv = tid >> 6, l15 = lane & 15, lg = lane >> 4;

  #pragma unroll
  for (int it = 0; it < 12; ++it) {
    int idx = tid + it * 256;
    int c = idx >> 4, q = idx & 15;
    float4 v = *(const float4*)(x + ((size_t)(b * CC + c)) * NN + n0 + q * 4);
    Xs[q * 4 + 0][c] = f2h(v.x); Xs[q * 4 + 1][c] = f2h(v.y);
    Xs[q * 4 + 2][c] = f2h(v.z); Xs[q * 4 + 3][c] = f2h(v.w);
  }

  for (int p = 0; p < 3; ++p) {
    const float* w    = (p == 0) ? th_w : (p == 1) ? ph_w : g_w;
    const float* bias = (p == 0) ? th_b : (p == 1) ? ph_b : g_b;
    const float scale = (p == 0) ? LOG2E : 1.0f;
    __syncthreads();
    #pragma unroll
    for (int it = 0; it < 18; ++it) {
      int idx = tid + it * 256;
      int r = idx / 48, q = idx % 48;
      float4 v = *(const float4*)(w + r * CC + q * 4);
      u16x4 hh; hh[0] = f2h(v.x * scale); hh[1] = f2h(v.y * scale);
      hh[2] = f2h(v.z * scale); hh[3] = f2h(v.w * scale);
      *(u16x4*)&Ws[r][q * 4] = hh;
    }
    __syncthreads();

    f32x4 acc[6];
    #pragma unroll
    for (int of = 0; of < 6; ++of) acc[of] = (f32x4){0.f, 0.f, 0.f, 0.f};
    #pragma unroll
    for (int ks = 0; ks < 6; ++ks) {
      h16x8 xa = *(const h16x8*)&Xs[wv * 16 + l15][ks * 32 + lg * 8];
      #pragma unroll
      for (int of = 0; of < 6; ++of) {
        h16x8 wf = *(const h16x8*)&Ws[of * 16 + l15][ks * 32 + lg * 8];
        if (p < 2) acc[of] = __builtin_amdgcn_mfma_f32_16x16x32_f16(xa, wf, acc[of], 0, 0, 0);
        else       acc[of] = __builtin_amdgcn_mfma_f32_16x16x32_f16(wf, xa, acc[of], 0, 0, 0);
      }
    }

    if (p < 2) {   // C[n][o] -> QB / KA (A/B-frag preswizzle)
      u16* dst = (p == 0) ? QB : KA;
      #pragma unroll
      for (int of = 0; of < 6; ++of) {
        int o = of * 16 + l15;
        float bo = bias[o] * scale;
        int kch = of * 2 + (l15 >> 3);
        #pragma unroll
        for (int r = 0; r < 4; ++r) {
          int n = n0 + wv * 16 + lg * 4 + r;
          int idx = (b * 128 + (n >> 5)) * 3072 + (kch * 32 + (n & 31)) * 8 + (o & 7);
          dst[idx] = f2h(acc[of][r] + bo);
        }
      }
    } else {       // C[o][m] -> VA (V^T A-frag preswizzle)
      #pragma unroll
      for (int of = 0; of < 6; ++of) {
        #pragma unroll
        for (int r = 0; r < 4; ++r) {
          int o = of * 16 + lg * 4 + r;
          int m = n0 + wv * 16 + l15;
          int idx = (b * 256 + (m >> 4)) * 1536 +
                    (((o >> 5) * 2 + ((m >> 3) & 1)) * 32 + (o & 31)) * 8 + (m & 7);
          VA[idx] = f2h(acc[of][r] + bias[o]);
        }
      }
    }
  }
}

// ---------------- Kernel 2: flash attention core ----------------
// 4 waves x 32 q-rows, NO LDS, NO barriers: K/V fragments are read directly from
// L2 (KV = 1.57 MB/batch, L2-resident; XCD swizzle keeps each batch on one XCD).
// Per-chunk softmax (r6 structure) so PV(c) overlaps softmax/loads of c+1.
__global__ __launch_bounds__(256, 2) void attn_kernel(
    const u16* __restrict__ QB, const u16* __restrict__ KA,
    const u16* __restrict__ VA, u16* __restrict__ yP, float* __restrict__ ml)
{
  const int b   = blockIdx.x;           // XCD-swizzle: id%8 == batch
  const int qt  = blockIdx.y;
  const int sp  = blockIdx.z;
  const int tid = threadIdx.x;
  const int lane = tid & 63;
  const int wv  = tid >> 6;
  const int l31 = lane & 31;
  const int h   = lane >> 5;

  const int t_start = (64 * sp) / NSPLIT;
  const int t_end   = (64 * (sp + 1)) / NSPLIT;

  const int nc = qt * 4 + wv;
  const u16* qb = QB + (size_t)(b * 128 + nc) * 3072;
  h16x8 qf[6];
  #pragma unroll
  for (int ks = 0; ks < 6; ++ks)
    qf[ks] = *(const h16x8*)(qb + ((ks * 2 + h) * 32 + l31) * 8);

  const u16* KAb = KA + (size_t)b * (128 * 3072);
  const u16* VAb = VA + (size_t)b * (256 * 1536);

  f32x16 acc[3];
  #pragma unroll
  for (int ob = 0; ob < 3; ++ob)
    #pragma unroll
    for (int i = 0; i < 16; ++i) acc[ob][i] = 0.f;
  float m_run = -3.0e38f, l_run = 0.f;   // log2-domain running max

  for (int t = t_start; t < t_end; ++t) {
    const u16* kt = KAb + (size_t)t * 6144;
    const u16* vt = VAb + (size_t)t * 6144;
    #pragma unroll
    for (int c = 0; c < 2; ++c) {
      const u16* kc = kt + c * 3072;
      const u16* vc = vt + c * 3072;
      // QK^T (swapped): S^T[m][n], lane holds col n=l31
      f32x16 S;
      #pragma unroll
      for (int i = 0; i < 16; ++i) S[i] = 0.f;
      #pragma unroll
      for (int ks = 0; ks < 6; ++ks) {
        h16x8 kf = *(const h16x8*)(kc + ((ks * 2 + h) * 32 + l31) * 8);
        S = __builtin_amdgcn_mfma_f32_32x32x16_f16(kf, qf[ks], S, 0, 0, 0);
      }
      // chunk max: in-reg max3 tree + cross-half combine
      float t0 = max3f(S[0], S[1], S[2]),   t1 = max3f(S[3], S[4], S[5]);
      float t2 = max3f(S[6], S[7], S[8]),   t3 = max3f(S[9], S[10], S[11]);
      float t4 = max3f(S[12], S[13], S[14]);
      float pmax = half_combine_max(fmaxf(max3f(t0, t1, t2), max3f(t3, t4, S[15])));
      // defer-max rescale (8 nats = 11.54 bits; P bounded by 2^11.54 < fp16 max)
      if (__ballot(pmax > m_run + 11.5416f)) {
        float mn = fmaxf(m_run, pmax);
        float sc = exp2f(m_run - mn);
        m_run = mn; l_run *= sc;
        #pragma unroll
        for (int ob = 0; ob < 3; ++ob)
          #pragma unroll
          for (int i = 0; i < 16; ++i) acc[ob][i] *= sc;
      }
      // P = exp2(S - m), row sum
      float p[16], v[16];
      #pragma unroll
      for (int i = 0; i < 16; ++i) p[i] = exp2f(S[i] - m_run);
      #pragma unroll
      for (int i = 0; i < 16; ++i) v[i] = p[i];
      #pragma unroll
      for (int st = 8; st >= 1; st >>= 1)
        #pragma unroll
        for (int i = 0; i < 8; ++i) if (i < st) v[i] += v[i + st];
      l_run += half_combine_sum(v[0]);
      // P -> B-frags: cvt_pk pairs then half-swaps
      u32 pk[8];
      #pragma unroll
      for (int i = 0; i < 8; ++i)
        pk[i] = __builtin_bit_cast(u32, __builtin_amdgcn_cvt_pkrtz(p[2 * i], p[2 * i + 1]));
      plane_swap(pk[0], pk[2]); plane_swap(pk[1], pk[3]);
      plane_swap(pk[4], pk[6]); plane_swap(pk[5], pk[7]);
      u32x4 bw0 = {pk[0], pk[1], pk[2], pk[3]};
      u32x4 bw1 = {pk[4], pk[5], pk[6], pk[7]};
      h16x8 pf0 = __builtin_bit_cast(h16x8, bw0);
      h16x8 pf1 = __builtin_bit_cast(h16x8, bw1);
      // PV: y^T[o][n] += V^T[o][m] * P^T[m][n]; 3 independent acc chains
      #pragma unroll
      for (int s2 = 0; s2 < 2; ++s2) {
        h16x8 pfr = s2 ? pf1 : pf0;
        #pragma unroll
        for (int ob = 0; ob < 3; ++ob) {
          h16x8 vf = *(const h16x8*)(vc + (((s2 * 3 + ob) * 2 + h) * 32 + l31) * 8);
          acc[ob] = __builtin_amdgcn_mfma_f32_32x32x16_f16(vf, pfr, acc[ob], 0, 0, 0);
        }
      }
    }
  }

  // epilogue: normalized partial + (m,l) per row (log2-domain m)
  float inv = 1.0f / l_run;
  int nglob = nc * 32 + l31;
  u16* yp = yP + (((size_t)sp * NB + b) * NN + nglob) * OO;
  #pragma unroll
  for (int ob = 0; ob < 3; ++ob) {
    #pragma unroll
    for (int rq = 0; rq < 4; ++rq) {
      int o0 = ob * 32 + rq * 8 + h * 4;
      u32 w0 = __builtin_bit_cast(u32,
          __builtin_amdgcn_cvt_pkrtz(acc[ob][rq * 4 + 0] * inv, acc[ob][rq * 4 + 1] * inv));
      u32 w1 = __builtin_bit_cast(u32,
          __builtin_amdgcn_cvt_pkrtz(acc[ob][rq * 4 + 2] * inv, acc[ob][rq * 4 + 3] * inv));
      uint2 pr; pr.x = w0; pr.y = w1;
      *(uint2*)&yp[o0] = pr;
    }
  }
  if (h == 0) {
    float2 v2; v2.x = m_run; v2.y = l_run;
    *(float2*)&ml[(((size_t)sp * NB + b) * NN + nglob) * 2] = v2;
  }
}

// ---------------- Kernel 3: merge partials + W projection + residual ----------------
#define YPAD 104
__global__ __launch_bounds__(256) void outproj_kernel(
    const float* __restrict__ x, const float* __restrict__ Ww,
    const float* __restrict__ Wb, const u16* __restrict__ yP,
    const float* __restrict__ ml, float* __restrict__ out)
{
  __shared__ __align__(16) u16 Wws[CC][YPAD];
  __shared__ __align__(16) u16 Ys[64][YPAD];
  const int b = blockIdx.y, n0 = blockIdx.x * 64, tid = threadIdx.x;
  const int lane = tid & 63, wv = tid >> 6, l15 = lane & 15, lg = lane >> 4;
  const size_t SB = (size_t)NB * NN;

  #pragma unroll
  for (int it = 0; it < 18; ++it) {
    int idx = tid + it * 256;
    int r = idx / 24, q = idx % 24;
    float4 v = *(const float4*)(Ww + r * OO + q * 4);
    u16x4 hh; hh[0] = f2h(v.x); hh[1] = f2h(v.y); hh[2] = f2h(v.z); hh[3] = f2h(v.w);
    *(u16x4*)&Wws[r][q * 4] = hh;
  }
  // stage Ys with in-register 3-way flash merge
  #pragma unroll
  for (int it = 0; it < 3; ++it) {
    int idx = tid + it * 256;
    int n = idx / 12, q = idx % 12;
    size_t bn = (size_t)b * NN + n0 + n;
    float m0 = ml[(0 * SB + bn) * 2], l0 = ml[(0 * SB + bn) * 2 + 1];
    float m1 = ml[(1 * SB + bn) * 2], l1 = ml[(1 * SB + bn) * 2 + 1];
    float m2 = ml[(2 * SB + bn) * 2], l2 = ml[(2 * SB + bn) * 2 + 1];
    float M = max3f(m0, m1, m2);
    float w0 = l0 * exp2f(m0 - M), w1 = l1 * exp2f(m1 - M), w2 = l2 * exp2f(m2 - M);
    float rinv = 1.0f / (w0 + w1 + w2);
    w0 *= rinv; w1 *= rinv; w2 *= rinv;
    h16x8 y0 = *(const h16x8*)(yP + (0 * SB + bn) * OO + q * 8);
    h16x8 y1 = *(const h16x8*)(yP + (1 * SB + bn) * OO + q * 8);
    h16x8 y2 = *(const h16x8*)(yP + (2 * SB + bn) * OO + q * 8);
    u32x4 packed;
    #pragma unroll
    for (int e = 0; e < 4; ++e) {
      float a = w0 * (float)y0[2 * e]     + w1 * (float)y1[2 * e]     + w2 * (float)y2[2 * e];
      float c = w0 * (float)y0[2 * e + 1] + w1 * (float)y1[2 * e + 1] + w2 * (float)y2[2 * e + 1];
      packed[e] = __builtin_bit_cast(u32, __builtin_amdgcn_cvt_pkrtz(a, c));
    }
    *(u32x4*)&Ys[n][q * 8] = packed;
  }
  __syncthreads();

  f32x4 acc[12];
  #pragma unroll
  for (int cf = 0; cf < 12; ++cf) acc[cf] = (f32x4){0.f, 0.f, 0.f, 0.f};
  #pragma unroll
  for (int ks = 0; ks < 3; ++ks) {
    h16x8 yb = *(const h16x8*)&Ys[wv * 16 + l15][ks * 32 + lg * 8];
    #pragma unroll
    for (int cf = 0; cf < 12; ++cf) {
      h16x8 wa = *(const h16x8*)&Wws[cf * 16 + l15][ks * 32 + lg * 8];
      acc[cf] = __builtin_amdgcn_mfma_f32_16x16x32_f16(wa, yb, acc[cf], 0, 0, 0);
    }
  }
  #pragma unroll
  for (int cf = 0; cf < 12; ++cf) {
    #pragma unroll
    for (int r = 0; r < 4; ++r) {
      int c = cf * 16 + lg * 4 + r;
      size_t off = ((size_t)(b * CC + c)) * NN + n0 + wv * 16 + l15;
      out[off] = acc[cf][r] + x[off] + Wb[c];
    }
  }
}

extern "C" void kernel_launch(void* const* d_in, const int* in_sizes, int n_in,
                              void* d_out, int out_size, void* d_ws, size_t ws_size,
                              hipStream_t stream) {
  const float* x    = (const float*)d_in[0];
  const float* g_w  = (const float*)d_in[1];
  const float* g_b  = (const float*)d_in[2];
  const float* th_w = (const float*)d_in[3];
  const float* th_b = (const float*)d_in[4];
  const float* ph_w = (const float*)d_in[5];
  const float* ph_b = (const float*)d_in[6];
  const float* W_w  = (const float*)d_in[7];
  const float* W_b  = (const float*)d_in[8];
  float* out = (float*)d_out;

  char* ws = (char*)d_ws;
  const size_t projB = (size_t)NB * NN * OO * sizeof(u16);   // 6.29 MB
  u16* QB   = (u16*)ws;
  u16* KA   = (u16*)(ws + projB);
  u16* VA   = (u16*)(ws + 2 * projB);
  u16* yP   = (u16*)(ws + 3 * projB);                        // 3 * projB
  float* ml = (float*)(ws + 6 * projB);                      // 786 KB

  dim3 blk(256);
  dim3 gproj(64, NB);
  hipLaunchKernelGGL(proj_kernel, gproj, blk, 0, stream,
                     x, g_w, g_b, th_w, th_b, ph_w, ph_b, QB, KA, VA);
  dim3 gattn(NB, 32, NSPLIT);
  hipLaunchKernelGGL(attn_kernel, gattn, blk, 0, stream, QB, KA, VA, yP, ml);
  dim3 gout(64, NB);
  hipLaunchKernelGGL(outproj_kernel, gout, blk, 0, stream, x, W_w, W_b, yP, ml, out);
}

// Round 9
// 108.801 us; speedup vs baseline: 1.1832x; 1.1832x over previous
//
#include <hip/hip_runtime.h>

typedef unsigned short u16;
typedef unsigned int u32;
typedef float f32x4 __attribute__((ext_vector_type(4)));
typedef float f32x16 __attribute__((ext_vector_type(16)));
typedef _Float16 h16x8 __attribute__((ext_vector_type(8)));
typedef u32 u32x4 __attribute__((ext_vector_type(4)));
typedef u32 u32x2 __attribute__((ext_vector_type(2)));
typedef u16 u16x4 __attribute__((ext_vector_type(4)));

#define NB 8
#define CC 192
#define OO 96
#define NN 4096
#define NSPLIT 4
#define XPAD 200   // proj LDS row pad
#define LOG2E 1.4426950408889634f

static __device__ __forceinline__ u16 f2h(float f) {
  _Float16 h = (_Float16)f;
  return __builtin_bit_cast(u16, h);
}
static __device__ __forceinline__ void gl_lds16(const u16* g, u16* l) {
  __builtin_amdgcn_global_load_lds(
      (const __attribute__((address_space(1))) void*)g,
      (__attribute__((address_space(3))) void*)l, 16, 0, 0);
}
// ret0 = [a.lanes0-31 | b.lanes0-31], ret1 = [a.lanes32-63 | b.lanes32-63]
static __device__ __forceinline__ void plane_swap(u32& a, u32& b) {
  u32x2 r = __builtin_amdgcn_permlane32_swap(a, b, false, false);
  a = r[0]; b = r[1];
}
static __device__ __forceinline__ float half_combine_max(float x) {
  u32 a = __builtin_bit_cast(u32, x), b = a;
  plane_swap(a, b);
  return fmaxf(__builtin_bit_cast(float, a), __builtin_bit_cast(float, b));
}
static __device__ __forceinline__ float half_combine_sum(float x) {
  u32 a = __builtin_bit_cast(u32, x), b = a;
  plane_swap(a, b);
  return __builtin_bit_cast(float, a) + __builtin_bit_cast(float, b);
}
static __device__ __forceinline__ float max3f(float a, float b, float c) {
  return fmaxf(fmaxf(a, b), c);   // clang fuses to v_max3_f32
}

// ---------------- Kernel 1: theta/phi/g projections as fp16 MFMA GEMMs ----------------
// Outputs in MFMA-fragment-preswizzled layouts (32x32x16 frags). Theta side is
// pre-scaled by log2(e) so attention can use native exp2.
__global__ __launch_bounds__(256) void proj_kernel(
    const float* __restrict__ x,
    const float* __restrict__ g_w, const float* __restrict__ g_b,
    const float* __restrict__ th_w, const float* __restrict__ th_b,
    const float* __restrict__ ph_w, const float* __restrict__ ph_b,
    u16* __restrict__ QB, u16* __restrict__ KA, u16* __restrict__ VA)
{
  __shared__ __align__(16) u16 Xs[64][XPAD];
  __shared__ __align__(16) u16 Ws[96][XPAD];
  const int b = blockIdx.y, n0 = blockIdx.x * 64, tid = threadIdx.x;
  const int lane = tid & 63, wv = tid >> 6, l15 = lane & 15, lg = lane >> 4;

  #pragma unroll
  for (int it = 0; it < 12; ++it) {
    int idx = tid + it * 256;
    int c = idx >> 4, q = idx & 15;
    float4 v = *(const float4*)(x + ((size_t)(b * CC + c)) * NN + n0 + q * 4);
    Xs[q * 4 + 0][c] = f2h(v.x); Xs[q * 4 + 1][c] = f2h(v.y);
    Xs[q * 4 + 2][c] = f2h(v.z); Xs[q * 4 + 3][c] = f2h(v.w);
  }

  for (int p = 0; p < 3; ++p) {
    const float* w    = (p == 0) ? th_w : (p == 1) ? ph_w : g_w;
    const float* bias = (p == 0) ? th_b : (p == 1) ? ph_b : g_b;
    const float scale = (p == 0) ? LOG2E : 1.0f;
    __syncthreads();
    #pragma unroll
    for (int it = 0; it < 18; ++it) {
      int idx = tid + it * 256;
      int r = idx / 48, q = idx % 48;
      float4 v = *(const float4*)(w + r * CC + q * 4);
      u16x4 hh; hh[0] = f2h(v.x * scale); hh[1] = f2h(v.y * scale);
      hh[2] = f2h(v.z * scale); hh[3] = f2h(v.w * scale);
      *(u16x4*)&Ws[r][q * 4] = hh;
    }
    __syncthreads();

    f32x4 acc[6];
    #pragma unroll
    for (int of = 0; of < 6; ++of) acc[of] = (f32x4){0.f, 0.f, 0.f, 0.f};
    #pragma unroll
    for (int ks = 0; ks < 6; ++ks) {
      h16x8 xa = *(const h16x8*)&Xs[wv * 16 + l15][ks * 32 + lg * 8];
      #pragma unroll
      for (int of = 0; of < 6; ++of) {
        h16x8 wf = *(const h16x8*)&Ws[of * 16 + l15][ks * 32 + lg * 8];
        if (p < 2) acc[of] = __builtin_amdgcn_mfma_f32_16x16x32_f16(xa, wf, acc[of], 0, 0, 0);
        else       acc[of] = __builtin_amdgcn_mfma_f32_16x16x32_f16(wf, xa, acc[of], 0, 0, 0);
      }
    }

    if (p < 2) {   // C[n][o] -> QB / KA (A/B-frag preswizzle)
      u16* dst = (p == 0) ? QB : KA;
      #pragma unroll
      for (int of = 0; of < 6; ++of) {
        int o = of * 16 + l15;
        float bo = bias[o] * scale;
        int kch = of * 2 + (l15 >> 3);
        #pragma unroll
        for (int r = 0; r < 4; ++r) {
          int n = n0 + wv * 16 + lg * 4 + r;
          int idx = (b * 128 + (n >> 5)) * 3072 + (kch * 32 + (n & 31)) * 8 + (o & 7);
          dst[idx] = f2h(acc[of][r] + bo);
        }
      }
    } else {       // C[o][m] -> VA (V^T A-frag preswizzle)
      #pragma unroll
      for (int of = 0; of < 6; ++of) {
        #pragma unroll
        for (int r = 0; r < 4; ++r) {
          int o = of * 16 + lg * 4 + r;
          int m = n0 + wv * 16 + l15;
          int idx = (b * 256 + (m >> 4)) * 1536 +
                    (((o >> 5) * 2 + ((m >> 3) & 1)) * 32 + (o & 31)) * 8 + (m & 7);
          VA[idx] = f2h(acc[of][r] + bias[o]);
        }
      }
    }
  }
}

// ---------------- Kernel 2: flash attention core (nq=2 per wave) ----------------
// 4 waves x 2 q-chunks (64 q-rows/wave). Each K/V fragment read from LDS feeds TWO
// MFMAs -> LDS bytes/MFMA halved vs r6. Per-chunk softmax; dbuf staging, counted vmcnt.
__global__ __launch_bounds__(256, 2) void attn_kernel(
    const u16* __restrict__ QB, const u16* __restrict__ KA,
    const u16* __restrict__ VA, u16* __restrict__ yP, float* __restrict__ ml)
{
  __shared__ __align__(16) u16 Ks[2][6144];
  __shared__ __align__(16) u16 Vs[2][6144];
  const int b   = blockIdx.x;           // XCD-swizzle: id%8 == batch
  const int qt  = blockIdx.y;           // 0..15
  const int sp  = blockIdx.z;           // 0..NSPLIT-1
  const int tid = threadIdx.x;
  const int lane = tid & 63;
  const int wv  = tid >> 6;
  const int l31 = lane & 31;
  const int h   = lane >> 5;

  const int t_start = 16 * sp;
  const int t_end   = 16 * (sp + 1);

  const int ncA = qt * 8 + wv * 2;
  const int ncB = ncA + 1;
  const u16* qbA = QB + (size_t)(b * 128 + ncA) * 3072;
  const u16* qbB = QB + (size_t)(b * 128 + ncB) * 3072;
  h16x8 qfA[6], qfB[6];
  #pragma unroll
  for (int ks = 0; ks < 6; ++ks) {
    qfA[ks] = *(const h16x8*)(qbA + ((ks * 2 + h) * 32 + l31) * 8);
    qfB[ks] = *(const h16x8*)(qbB + ((ks * 2 + h) * 32 + l31) * 8);
  }

  const u16* KAb = KA + (size_t)b * (128 * 3072);
  const u16* VAb = VA + (size_t)b * (256 * 1536);

  f32x16 accA[3], accB[3];
  #pragma unroll
  for (int ob = 0; ob < 3; ++ob)
    #pragma unroll
    for (int i = 0; i < 16; ++i) { accA[ob][i] = 0.f; accB[ob][i] = 0.f; }
  float mA = -3.0e38f, lA = 0.f;   // log2-domain running max/sum
  float mB = -3.0e38f, lB = 0.f;

  // prologue stage: tile = 12288 B; 256 thr x 16 B x 3 iters per operand
  {
    const u16* gk = KAb + (size_t)t_start * 6144;
    const u16* gv = VAb + (size_t)t_start * 6144;
    #pragma unroll
    for (int i = 0; i < 3; ++i) gl_lds16(gk + tid * 8 + i * 2048, &Ks[0][tid * 8 + i * 2048]);
    #pragma unroll
    for (int i = 0; i < 3; ++i) gl_lds16(gv + tid * 8 + i * 2048, &Vs[0][tid * 8 + i * 2048]);
  }

  for (int t = t_start; t < t_end; ++t) {
    const int bf = (t - t_start) & 1;
    if (t + 1 < t_end) {
      const u16* gk = KAb + (size_t)(t + 1) * 6144;
      const u16* gv = VAb + (size_t)(t + 1) * 6144;
      #pragma unroll
      for (int i = 0; i < 3; ++i) gl_lds16(gk + tid * 8 + i * 2048, &Ks[bf ^ 1][tid * 8 + i * 2048]);
      #pragma unroll
      for (int i = 0; i < 3; ++i) gl_lds16(gv + tid * 8 + i * 2048, &Vs[bf ^ 1][tid * 8 + i * 2048]);
      asm volatile("s_waitcnt vmcnt(6)" ::: "memory");   // drain current tile, keep 6 in flight
    } else {
      asm volatile("s_waitcnt vmcnt(0)" ::: "memory");
    }
    __builtin_amdgcn_s_barrier();
    __builtin_amdgcn_sched_barrier(0);

    #pragma unroll
    for (int c = 0; c < 2; ++c) {
      const u16* kc = &Ks[bf][c * 3072];
      const u16* vc = &Vs[bf][c * 3072];
      // QK^T both q-chunks: shared K frag, 2 independent MFMA chains
      f32x16 SA, SB;
      #pragma unroll
      for (int i = 0; i < 16; ++i) { SA[i] = 0.f; SB[i] = 0.f; }
      #pragma unroll
      for (int ks = 0; ks < 6; ++ks) {
        h16x8 kf = *(const h16x8*)(kc + ((ks * 2 + h) * 32 + l31) * 8);
        SA = __builtin_amdgcn_mfma_f32_32x32x16_f16(kf, qfA[ks], SA, 0, 0, 0);
        SB = __builtin_amdgcn_mfma_f32_32x32x16_f16(kf, qfB[ks], SB, 0, 0, 0);
      }

      // ---- softmax A ----
      u32 pkA[8];
      {
        float t0 = max3f(SA[0], SA[1], SA[2]),   t1 = max3f(SA[3], SA[4], SA[5]);
        float t2 = max3f(SA[6], SA[7], SA[8]),   t3 = max3f(SA[9], SA[10], SA[11]);
        float t4 = max3f(SA[12], SA[13], SA[14]);
        float pmax = half_combine_max(fmaxf(max3f(t0, t1, t2), max3f(t3, t4, SA[15])));
        if (__ballot(pmax > mA + 11.5416f)) {   // defer-max (8 nats)
          float mn = fmaxf(mA, pmax);
          float sc = exp2f(mA - mn);
          mA = mn; lA *= sc;
          #pragma unroll
          for (int ob = 0; ob < 3; ++ob)
            #pragma unroll
            for (int i = 0; i < 16; ++i) accA[ob][i] *= sc;
        }
        #pragma unroll
        for (int i = 0; i < 16; ++i) SA[i] = exp2f(SA[i] - mA);
        #pragma unroll
        for (int i = 0; i < 8; ++i)
          pkA[i] = __builtin_bit_cast(u32, __builtin_amdgcn_cvt_pkrtz(SA[2 * i], SA[2 * i + 1]));
        #pragma unroll
        for (int st = 8; st >= 1; st >>= 1)
          #pragma unroll
          for (int i = 0; i < 8; ++i) if (i < st) SA[i] += SA[i + st];
        lA += half_combine_sum(SA[0]);
        plane_swap(pkA[0], pkA[2]); plane_swap(pkA[1], pkA[3]);
        plane_swap(pkA[4], pkA[6]); plane_swap(pkA[5], pkA[7]);
      }
      // ---- softmax B ----
      u32 pkB[8];
      {
        float t0 = max3f(SB[0], SB[1], SB[2]),   t1 = max3f(SB[3], SB[4], SB[5]);
        float t2 = max3f(SB[6], SB[7], SB[8]),   t3 = max3f(SB[9], SB[10], SB[11]);
        float t4 = max3f(SB[12], SB[13], SB[14]);
        float pmax = half_combine_max(fmaxf(max3f(t0, t1, t2), max3f(t3, t4, SB[15])));
        if (__ballot(pmax > mB + 11.5416f)) {
          float mn = fmaxf(mB, pmax);
          float sc = exp2f(mB - mn);
          mB = mn; lB *= sc;
          #pragma unroll
          for (int ob = 0; ob < 3; ++ob)
            #pragma unroll
            for (int i = 0; i < 16; ++i) accB[ob][i] *= sc;
        }
        #pragma unroll
        for (int i = 0; i < 16; ++i) SB[i] = exp2f(SB[i] - mB);
        #pragma unroll
        for (int i = 0; i < 8; ++i)
          pkB[i] = __builtin_bit_cast(u32, __builtin_amdgcn_cvt_pkrtz(SB[2 * i], SB[2 * i + 1]));
        #pragma unroll
        for (int st = 8; st >= 1; st >>= 1)
          #pragma unroll
          for (int i = 0; i < 8; ++i) if (i < st) SB[i] += SB[i + st];
        lB += half_combine_sum(SB[0]);
        plane_swap(pkB[0], pkB[2]); plane_swap(pkB[1], pkB[3]);
        plane_swap(pkB[4], pkB[6]); plane_swap(pkB[5], pkB[7]);
      }
      u32x4 a0 = {pkA[0], pkA[1], pkA[2], pkA[3]}, a1 = {pkA[4], pkA[5], pkA[6], pkA[7]};
      u32x4 b0 = {pkB[0], pkB[1], pkB[2], pkB[3]}, b1 = {pkB[4], pkB[5], pkB[6], pkB[7]};
      h16x8 pfA[2] = {__builtin_bit_cast(h16x8, a0), __builtin_bit_cast(h16x8, a1)};
      h16x8 pfB[2] = {__builtin_bit_cast(h16x8, b0), __builtin_bit_cast(h16x8, b1)};

      // PV both q-chunks: each V frag read feeds 2 MFMAs
      #pragma unroll
      for (int s2 = 0; s2 < 2; ++s2) {
        #pragma unroll
        for (int ob = 0; ob < 3; ++ob) {
          h16x8 vf = *(const h16x8*)(vc + (((s2 * 3 + ob) * 2 + h) * 32 + l31) * 8);
          accA[ob] = __builtin_amdgcn_mfma_f32_32x32x16_f16(vf, pfA[s2], accA[ob], 0, 0, 0);
          accB[ob] = __builtin_amdgcn_mfma_f32_32x32x16_f16(vf, pfB[s2], accB[ob], 0, 0, 0);
        }
      }
    }
    __builtin_amdgcn_s_barrier();
    __builtin_amdgcn_sched_barrier(0);
  }

  // epilogue: normalized partials + (m,l) per row (log2-domain m)
  #pragma unroll
  for (int qq = 0; qq < 2; ++qq) {
    const f32x16* acc = qq ? accB : accA;
    float mR = qq ? mB : mA, lR = qq ? lB : lA;
    float inv = 1.0f / lR;
    int nglob = (qq ? ncB : ncA) * 32 + l31;
    u16* yp = yP + (((size_t)sp * NB + b) * NN + nglob) * OO;
    #pragma unroll
    for (int ob = 0; ob < 3; ++ob) {
      #pragma unroll
      for (int rq = 0; rq < 4; ++rq) {
        int o0 = ob * 32 + rq * 8 + h * 4;
        u32 w0 = __builtin_bit_cast(u32,
            __builtin_amdgcn_cvt_pkrtz(acc[ob][rq * 4 + 0] * inv, acc[ob][rq * 4 + 1] * inv));
        u32 w1 = __builtin_bit_cast(u32,
            __builtin_amdgcn_cvt_pkrtz(acc[ob][rq * 4 + 2] * inv, acc[ob][rq * 4 + 3] * inv));
        uint2 pr; pr.x = w0; pr.y = w1;
        *(uint2*)&yp[o0] = pr;
      }
    }
    if (h == 0) {
      float2 v2; v2.x = mR; v2.y = lR;
      *(float2*)&ml[(((size_t)sp * NB + b) * NN + nglob) * 2] = v2;
    }
  }
}

// ---------------- Kernel 3: merge partials + W projection + residual ----------------
#define YPAD 104
__global__ __launch_bounds__(256) void outproj_kernel(
    const float* __restrict__ x, const float* __restrict__ Ww,
    const float* __restrict__ Wb, const u16* __restrict__ yP,
    const float* __restrict__ ml, float* __restrict__ out)
{
  __shared__ __align__(16) u16 Wws[CC][YPAD];
  __shared__ __align__(16) u16 Ys[64][YPAD];
  const int b = blockIdx.y, n0 = blockIdx.x * 64, tid = threadIdx.x;
  const int lane = tid & 63, wv = tid >> 6, l15 = lane & 15, lg = lane >> 4;
  const size_t SB = (size_t)NB * NN;

  #pragma unroll
  for (int it = 0; it < 18; ++it) {
    int idx = tid + it * 256;
    int r = idx / 24, q = idx % 24;
    float4 v = *(const float4*)(Ww + r * OO + q * 4);
    u16x4 hh; hh[0] = f2h(v.x); hh[1] = f2h(v.y); hh[2] = f2h(v.z); hh[3] = f2h(v.w);
    *(u16x4*)&Wws[r][q * 4] = hh;
  }
  // stage Ys with in-register NSPLIT-way flash merge
  #pragma unroll
  for (int it = 0; it < 3; ++it) {
    int idx = tid + it * 256;
    int n = idx / 12, q = idx % 12;
    size_t bn = (size_t)b * NN + n0 + n;
    float mm[NSPLIT], ll[NSPLIT];
    float M = -3.0e38f;
    #pragma unroll
    for (int s = 0; s < NSPLIT; ++s) {
      mm[s] = ml[((size_t)s * SB + bn) * 2];
      ll[s] = ml[((size_t)s * SB + bn) * 2 + 1];
      M = fmaxf(M, mm[s]);
    }
    float wsum = 0.f, w[NSPLIT];
    #pragma unroll
    for (int s = 0; s < NSPLIT; ++s) { w[s] = ll[s] * exp2f(mm[s] - M); wsum += w[s]; }
    float rinv = 1.0f / wsum;
    #pragma unroll
    for (int s = 0; s < NSPLIT; ++s) w[s] *= rinv;
    float accv[8];
    #pragma unroll
    for (int e = 0; e < 8; ++e) accv[e] = 0.f;
    #pragma unroll
    for (int s = 0; s < NSPLIT; ++s) {
      h16x8 ys = *(const h16x8*)(yP + ((size_t)s * SB + bn) * OO + q * 8);
      #pragma unroll
      for (int e = 0; e < 8; ++e) accv[e] += w[s] * (float)ys[e];
    }
    u32x4 packed;
    #pragma unroll
    for (int e = 0; e < 4; ++e)
      packed[e] = __builtin_bit_cast(u32,
          __builtin_amdgcn_cvt_pkrtz(accv[2 * e], accv[2 * e + 1]));
    *(u32x4*)&Ys[n][q * 8] = packed;
  }
  __syncthreads();

  f32x4 acc[12];
  #pragma unroll
  for (int cf = 0; cf < 12; ++cf) acc[cf] = (f32x4){0.f, 0.f, 0.f, 0.f};
  #pragma unroll
  for (int ks = 0; ks < 3; ++ks) {
    h16x8 yb = *(const h16x8*)&Ys[wv * 16 + l15][ks * 32 + lg * 8];
    #pragma unroll
    for (int cf = 0; cf < 12; ++cf) {
      h16x8 wa = *(const h16x8*)&Wws[cf * 16 + l15][ks * 32 + lg * 8];
      acc[cf] = __builtin_amdgcn_mfma_f32_16x16x32_f16(wa, yb, acc[cf], 0, 0, 0);
    }
  }
  #pragma unroll
  for (int cf = 0; cf < 12; ++cf) {
    #pragma unroll
    for (int r = 0; r < 4; ++r) {
      int c = cf * 16 + lg * 4 + r;
      size_t off = ((size_t)(b * CC + c)) * NN + n0 + wv * 16 + l15;
      out[off] = acc[cf][r] + x[off] + Wb[c];
    }
  }
}

extern "C" void kernel_launch(void* const* d_in, const int* in_sizes, int n_in,
                              void* d_out, int out_size, void* d_ws, size_t ws_size,
                              hipStream_t stream) {
  const float* x    = (const float*)d_in[0];
  const float* g_w  = (const float*)d_in[1];
  const float* g_b  = (const float*)d_in[2];
  const float* th_w = (const float*)d_in[3];
  const float* th_b = (const float*)d_in[4];
  const float* ph_w = (const float*)d_in[5];
  const float* ph_b = (const float*)d_in[6];
  const float* W_w  = (const float*)d_in[7];
  const float* W_b  = (const float*)d_in[8];
  float* out = (float*)d_out;

  char* ws = (char*)d_ws;
  const size_t projB = (size_t)NB * NN * OO * sizeof(u16);   // 6.29 MB
  u16* QB   = (u16*)ws;
  u16* KA   = (u16*)(ws + projB);
  u16* VA   = (u16*)(ws + 2 * projB);
  u16* yP   = (u16*)(ws + 3 * projB);                        // NSPLIT * projB
  float* ml = (float*)(ws + (3 + NSPLIT) * projB);           // 1.05 MB

  dim3 blk(256);
  dim3 gproj(64, NB);
  hipLaunchKernelGGL(proj_kernel, gproj, blk, 0, stream,
                     x, g_w, g_b, th_w, th_b, ph_w, ph_b, QB, KA, VA);
  dim3 gattn(NB, 16, NSPLIT);
  hipLaunchKernelGGL(attn_kernel, gattn, blk, 0, stream, QB, KA, VA, yP, ml);
  dim3 gout(64, NB);
  hipLaunchKernelGGL(outproj_kernel, gout, blk, 0, stream, x, W_w, W_b, yP, ml, out);
}

// Round 10
// 97.844 us; speedup vs baseline: 1.3157x; 1.1120x over previous
//
#include <hip/hip_runtime.h>

typedef unsigned short u16;
typedef unsigned int u32;
typedef float f32x4 __attribute__((ext_vector_type(4)));
typedef float f32x16 __attribute__((ext_vector_type(16)));
typedef _Float16 h16x8 __attribute__((ext_vector_type(8)));
typedef u32 u32x4 __attribute__((ext_vector_type(4)));
typedef u32 u32x2 __attribute__((ext_vector_type(2)));
typedef u16 u16x4 __attribute__((ext_vector_type(4)));

#define NB 8
#define CC 192
#define OO 96
#define NN 4096
#define NSPLIT 4
#define XPAD 200   // proj LDS row pad
#define LOG2E 1.4426950408889634f

static __device__ __forceinline__ u16 f2h(float f) {
  _Float16 h = (_Float16)f;
  return __builtin_bit_cast(u16, h);
}
static __device__ __forceinline__ void gl_lds16(const u16* g, u16* l) {
  __builtin_amdgcn_global_load_lds(
      (const __attribute__((address_space(1))) void*)g,
      (__attribute__((address_space(3))) void*)l, 16, 0, 0);
}
// raw v_exp_f32: D = 2^S (1 instr; libm exp2f lowers to ~5)
static __device__ __forceinline__ float exp2_raw(float x) {
  float r;
  asm("v_exp_f32 %0, %1" : "=v"(r) : "v"(x));
  return r;
}
// ret0 = [a.lanes0-31 | b.lanes0-31], ret1 = [a.lanes32-63 | b.lanes32-63]
static __device__ __forceinline__ void plane_swap(u32& a, u32& b) {
  u32x2 r = __builtin_amdgcn_permlane32_swap(a, b, false, false);
  a = r[0]; b = r[1];
}
static __device__ __forceinline__ float half_combine_max(float x) {
  u32 a = __builtin_bit_cast(u32, x), b = a;
  plane_swap(a, b);
  return fmaxf(__builtin_bit_cast(float, a), __builtin_bit_cast(float, b));
}
static __device__ __forceinline__ float half_combine_sum(float x) {
  u32 a = __builtin_bit_cast(u32, x), b = a;
  plane_swap(a, b);
  return __builtin_bit_cast(float, a) + __builtin_bit_cast(float, b);
}
static __device__ __forceinline__ float max3f(float a, float b, float c) {
  return fmaxf(fmaxf(a, b), c);   // clang fuses to v_max3_f32
}

// ---------------- Kernel 1: theta/phi/g projections as fp16 MFMA GEMMs ----------------
// Outputs in MFMA-fragment-preswizzled layouts (32x32x16 frags). Theta side is
// pre-scaled by log2(e) so attention can use native exp2.
__global__ __launch_bounds__(256) void proj_kernel(
    const float* __restrict__ x,
    const float* __restrict__ g_w, const float* __restrict__ g_b,
    const float* __restrict__ th_w, const float* __restrict__ th_b,
    const float* __restrict__ ph_w, const float* __restrict__ ph_b,
    u16* __restrict__ QB, u16* __restrict__ KA, u16* __restrict__ VA)
{
  __shared__ __align__(16) u16 Xs[64][XPAD];
  __shared__ __align__(16) u16 Ws[96][XPAD];
  const int b = blockIdx.y, n0 = blockIdx.x * 64, tid = threadIdx.x;
  const int lane = tid & 63, wv = tid >> 6, l15 = lane & 15, lg = lane >> 4;

  #pragma unroll
  for (int it = 0; it < 12; ++it) {
    int idx = tid + it * 256;
    int c = idx >> 4, q = idx & 15;
    float4 v = *(const float4*)(x + ((size_t)(b * CC + c)) * NN + n0 + q * 4);
    Xs[q * 4 + 0][c] = f2h(v.x); Xs[q * 4 + 1][c] = f2h(v.y);
    Xs[q * 4 + 2][c] = f2h(v.z); Xs[q * 4 + 3][c] = f2h(v.w);
  }

  for (int p = 0; p < 3; ++p) {
    const float* w    = (p == 0) ? th_w : (p == 1) ? ph_w : g_w;
    const float* bias = (p == 0) ? th_b : (p == 1) ? ph_b : g_b;
    const float scale = (p == 0) ? LOG2E : 1.0f;
    __syncthreads();
    #pragma unroll
    for (int it = 0; it < 18; ++it) {
      int idx = tid + it * 256;
      int r = idx / 48, q = idx % 48;
      float4 v = *(const float4*)(w + r * CC + q * 4);
      u16x4 hh; hh[0] = f2h(v.x * scale); hh[1] = f2h(v.y * scale);
      hh[2] = f2h(v.z * scale); hh[3] = f2h(v.w * scale);
      *(u16x4*)&Ws[r][q * 4] = hh;
    }
    __syncthreads();

    f32x4 acc[6];
    #pragma unroll
    for (int of = 0; of < 6; ++of) acc[of] = (f32x4){0.f, 0.f, 0.f, 0.f};
    #pragma unroll
    for (int ks = 0; ks < 6; ++ks) {
      h16x8 xa = *(const h16x8*)&Xs[wv * 16 + l15][ks * 32 + lg * 8];
      #pragma unroll
      for (int of = 0; of < 6; ++of) {
        h16x8 wf = *(const h16x8*)&Ws[of * 16 + l15][ks * 32 + lg * 8];
        if (p < 2) acc[of] = __builtin_amdgcn_mfma_f32_16x16x32_f16(xa, wf, acc[of], 0, 0, 0);
        else       acc[of] = __builtin_amdgcn_mfma_f32_16x16x32_f16(wf, xa, acc[of], 0, 0, 0);
      }
    }

    if (p < 2) {   // C[n][o] -> QB / KA (A/B-frag preswizzle)
      u16* dst = (p == 0) ? QB : KA;
      #pragma unroll
      for (int of = 0; of < 6; ++of) {
        int o = of * 16 + l15;
        float bo = bias[o] * scale;
        int kch = of * 2 + (l15 >> 3);
        #pragma unroll
        for (int r = 0; r < 4; ++r) {
          int n = n0 + wv * 16 + lg * 4 + r;
          int idx = (b * 128 + (n >> 5)) * 3072 + (kch * 32 + (n & 31)) * 8 + (o & 7);
          dst[idx] = f2h(acc[of][r] + bo);
        }
      }
    } else {       // C[o][m] -> VA (V^T A-frag preswizzle)
      #pragma unroll
      for (int of = 0; of < 6; ++of) {
        #pragma unroll
        for (int r = 0; r < 4; ++r) {
          int o = of * 16 + lg * 4 + r;
          int m = n0 + wv * 16 + l15;
          int idx = (b * 256 + (m >> 4)) * 1536 +
                    (((o >> 5) * 2 + ((m >> 3) & 1)) * 32 + (o & 31)) * 8 + (m & 7);
          VA[idx] = f2h(acc[of][r] + bias[o]);
        }
      }
    }
  }
}

// ---------------- Kernel 2: flash attention core (nq=2, 2-wave blocks) ----------------
// 2 waves x 2 q-chunks (64 q/wave, 128 q/block). Single-buffer LDS tile (24 KB) ->
// 4 blocks/CU = 4 phase-diverse streams. Each K/V fragment read feeds 2 MFMAs.
__global__ __launch_bounds__(128, 2) void attn_kernel(
    const u16* __restrict__ QB, const u16* __restrict__ KA,
    const u16* __restrict__ VA, u16* __restrict__ yP, float* __restrict__ ml)
{
  __shared__ __align__(16) u16 Ks[6144];
  __shared__ __align__(16) u16 Vs[6144];
  const int b   = blockIdx.x;           // XCD-swizzle: id%8 == batch
  const int qt  = blockIdx.y;           // 0..31
  const int sp  = blockIdx.z;           // 0..NSPLIT-1
  const int tid = threadIdx.x;          // 0..127
  const int lane = tid & 63;
  const int wv  = tid >> 6;             // 0..1
  const int l31 = lane & 31;
  const int h   = lane >> 5;

  const int t_start = 16 * sp;
  const int t_end   = 16 * (sp + 1);

  const int ncA = qt * 4 + wv * 2;
  const int ncB = ncA + 1;
  const u16* qbA = QB + (size_t)(b * 128 + ncA) * 3072;
  const u16* qbB = QB + (size_t)(b * 128 + ncB) * 3072;
  h16x8 qfA[6], qfB[6];
  #pragma unroll
  for (int ks = 0; ks < 6; ++ks) {
    qfA[ks] = *(const h16x8*)(qbA + ((ks * 2 + h) * 32 + l31) * 8);
    qfB[ks] = *(const h16x8*)(qbB + ((ks * 2 + h) * 32 + l31) * 8);
  }

  const u16* gk = KA + (size_t)b * (128 * 3072) + (size_t)t_start * 6144;
  const u16* gv = VA + (size_t)b * (256 * 1536) + (size_t)t_start * 6144;

  f32x16 accA[3], accB[3];
  #pragma unroll
  for (int ob = 0; ob < 3; ++ob)
    #pragma unroll
    for (int i = 0; i < 16; ++i) { accA[ob][i] = 0.f; accB[ob][i] = 0.f; }
  float mA = -3.0e38f, lA = 0.f;   // log2-domain running max/sum
  float mB = -3.0e38f, lB = 0.f;

  for (int t = t_start; t < t_end; ++t) {
    // stage tile: K 12288 B + V 12288 B; 128 thr x 16 B x 6 iters each
    #pragma unroll
    for (int i = 0; i < 6; ++i) gl_lds16(gk + tid * 8 + i * 1024, &Ks[tid * 8 + i * 1024]);
    #pragma unroll
    for (int i = 0; i < 6; ++i) gl_lds16(gv + tid * 8 + i * 1024, &Vs[tid * 8 + i * 1024]);
    gk += 6144; gv += 6144;
    asm volatile("s_waitcnt vmcnt(0)" ::: "memory");
    __builtin_amdgcn_s_barrier();
    __builtin_amdgcn_sched_barrier(0);

    #pragma unroll
    for (int c = 0; c < 2; ++c) {
      const u16* kc = &Ks[c * 3072];
      const u16* vc = &Vs[c * 3072];
      // QK^T both q-chunks: shared K frag, 2 independent MFMA chains
      f32x16 SA, SB;
      #pragma unroll
      for (int i = 0; i < 16; ++i) { SA[i] = 0.f; SB[i] = 0.f; }
      #pragma unroll
      for (int ks = 0; ks < 6; ++ks) {
        h16x8 kf = *(const h16x8*)(kc + ((ks * 2 + h) * 32 + l31) * 8);
        SA = __builtin_amdgcn_mfma_f32_32x32x16_f16(kf, qfA[ks], SA, 0, 0, 0);
        SB = __builtin_amdgcn_mfma_f32_32x32x16_f16(kf, qfB[ks], SB, 0, 0, 0);
      }

      // ---- softmax A ----
      u32 pkA[8];
      {
        float t0 = max3f(SA[0], SA[1], SA[2]),   t1 = max3f(SA[3], SA[4], SA[5]);
        float t2 = max3f(SA[6], SA[7], SA[8]),   t3 = max3f(SA[9], SA[10], SA[11]);
        float t4 = max3f(SA[12], SA[13], SA[14]);
        float pmax = half_combine_max(fmaxf(max3f(t0, t1, t2), max3f(t3, t4, SA[15])));
        if (__ballot(pmax > mA + 11.5416f)) {   // defer-max (8 nats)
          float mn = fmaxf(mA, pmax);
          float sc = exp2_raw(mA - mn);
          mA = mn; lA *= sc;
          #pragma unroll
          for (int ob = 0; ob < 3; ++ob)
            #pragma unroll
            for (int i = 0; i < 16; ++i) accA[ob][i] *= sc;
        }
        #pragma unroll
        for (int i = 0; i < 16; ++i) SA[i] = exp2_raw(SA[i] - mA);
        #pragma unroll
        for (int i = 0; i < 8; ++i)
          pkA[i] = __builtin_bit_cast(u32, __builtin_amdgcn_cvt_pkrtz(SA[2 * i], SA[2 * i + 1]));
        #pragma unroll
        for (int st = 8; st >= 1; st >>= 1)
          #pragma unroll
          for (int i = 0; i < 8; ++i) if (i < st) SA[i] += SA[i + st];
        lA += half_combine_sum(SA[0]);
        plane_swap(pkA[0], pkA[2]); plane_swap(pkA[1], pkA[3]);
        plane_swap(pkA[4], pkA[6]); plane_swap(pkA[5], pkA[7]);
      }
      // ---- softmax B ----
      u32 pkB[8];
      {
        float t0 = max3f(SB[0], SB[1], SB[2]),   t1 = max3f(SB[3], SB[4], SB[5]);
        float t2 = max3f(SB[6], SB[7], SB[8]),   t3 = max3f(SB[9], SB[10], SB[11]);
        float t4 = max3f(SB[12], SB[13], SB[14]);
        float pmax = half_combine_max(fmaxf(max3f(t0, t1, t2), max3f(t3, t4, SB[15])));
        if (__ballot(pmax > mB + 11.5416f)) {
          float mn = fmaxf(mB, pmax);
          float sc = exp2_raw(mB - mn);
          mB = mn; lB *= sc;
          #pragma unroll
          for (int ob = 0; ob < 3; ++ob)
            #pragma unroll
            for (int i = 0; i < 16; ++i) accB[ob][i] *= sc;
        }
        #pragma unroll
        for (int i = 0; i < 16; ++i) SB[i] = exp2_raw(SB[i] - mB);
        #pragma unroll
        for (int i = 0; i < 8; ++i)
          pkB[i] = __builtin_bit_cast(u32, __builtin_amdgcn_cvt_pkrtz(SB[2 * i], SB[2 * i + 1]));
        #pragma unroll
        for (int st = 8; st >= 1; st >>= 1)
          #pragma unroll
          for (int i = 0; i < 8; ++i) if (i < st) SB[i] += SB[i + st];
        lB += half_combine_sum(SB[0]);
        plane_swap(pkB[0], pkB[2]); plane_swap(pkB[1], pkB[3]);
        plane_swap(pkB[4], pkB[6]); plane_swap(pkB[5], pkB[7]);
      }
      u32x4 a0 = {pkA[0], pkA[1], pkA[2], pkA[3]}, a1 = {pkA[4], pkA[5], pkA[6], pkA[7]};
      u32x4 b0 = {pkB[0], pkB[1], pkB[2], pkB[3]}, b1 = {pkB[4], pkB[5], pkB[6], pkB[7]};
      h16x8 pfA[2] = {__builtin_bit_cast(h16x8, a0), __builtin_bit_cast(h16x8, a1)};
      h16x8 pfB[2] = {__builtin_bit_cast(h16x8, b0), __builtin_bit_cast(h16x8, b1)};

      // PV both q-chunks: each V frag read feeds 2 MFMAs
      #pragma unroll
      for (int s2 = 0; s2 < 2; ++s2) {
        #pragma unroll
        for (int ob = 0; ob < 3; ++ob) {
          h16x8 vf = *(const h16x8*)(vc + (((s2 * 3 + ob) * 2 + h) * 32 + l31) * 8);
          accA[ob] = __builtin_amdgcn_mfma_f32_32x32x16_f16(vf, pfA[s2], accA[ob], 0, 0, 0);
          accB[ob] = __builtin_amdgcn_mfma_f32_32x32x16_f16(vf, pfB[s2], accB[ob], 0, 0, 0);
        }
      }
    }
    __builtin_amdgcn_s_barrier();   // all waves done reading before next stage
  }

  // epilogue: normalized partials + (m,l) per row (log2-domain m)
  #pragma unroll
  for (int qq = 0; qq < 2; ++qq) {
    const f32x16* acc = qq ? accB : accA;
    float mR = qq ? mB : mA, lR = qq ? lB : lA;
    float inv = 1.0f / lR;
    int nglob = (qq ? ncB : ncA) * 32 + l31;
    u16* yp = yP + (((size_t)sp * NB + b) * NN + nglob) * OO;
    #pragma unroll
    for (int ob = 0; ob < 3; ++ob) {
      #pragma unroll
      for (int rq = 0; rq < 4; ++rq) {
        int o0 = ob * 32 + rq * 8 + h * 4;
        u32 w0 = __builtin_bit_cast(u32,
            __builtin_amdgcn_cvt_pkrtz(acc[ob][rq * 4 + 0] * inv, acc[ob][rq * 4 + 1] * inv));
        u32 w1 = __builtin_bit_cast(u32,
            __builtin_amdgcn_cvt_pkrtz(acc[ob][rq * 4 + 2] * inv, acc[ob][rq * 4 + 3] * inv));
        uint2 pr; pr.x = w0; pr.y = w1;
        *(uint2*)&yp[o0] = pr;
      }
    }
    if (h == 0) {
      float2 v2; v2.x = mR; v2.y = lR;
      *(float2*)&ml[(((size_t)sp * NB + b) * NN + nglob) * 2] = v2;
    }
  }
}

// ---------------- Kernel 3: merge partials + W projection + residual ----------------
#define YPAD 104
__global__ __launch_bounds__(256) void outproj_kernel(
    const float* __restrict__ x, const float* __restrict__ Ww,
    const float* __restrict__ Wb, const u16* __restrict__ yP,
    const float* __restrict__ ml, float* __restrict__ out)
{
  __shared__ __align__(16) u16 Wws[CC][YPAD];
  __shared__ __align__(16) u16 Ys[64][YPAD];
  const int b = blockIdx.y, n0 = blockIdx.x * 64, tid = threadIdx.x;
  const int lane = tid & 63, wv = tid >> 6, l15 = lane & 15, lg = lane >> 4;
  const size_t SB = (size_t)NB * NN;

  #pragma unroll
  for (int it = 0; it < 18; ++it) {
    int idx = tid + it * 256;
    int r = idx / 24, q = idx % 24;
    float4 v = *(const float4*)(Ww + r * OO + q * 4);
    u16x4 hh; hh[0] = f2h(v.x); hh[1] = f2h(v.y); hh[2] = f2h(v.z); hh[3] = f2h(v.w);
    *(u16x4*)&Wws[r][q * 4] = hh;
  }
  // stage Ys with in-register NSPLIT-way flash merge
  #pragma unroll
  for (int it = 0; it < 3; ++it) {
    int idx = tid + it * 256;
    int n = idx / 12, q = idx % 12;
    size_t bn = (size_t)b * NN + n0 + n;
    float mm[NSPLIT], ll[NSPLIT];
    float M = -3.0e38f;
    #pragma unroll
    for (int s = 0; s < NSPLIT; ++s) {
      mm[s] = ml[((size_t)s * SB + bn) * 2];
      ll[s] = ml[((size_t)s * SB + bn) * 2 + 1];
      M = fmaxf(M, mm[s]);
    }
    float wsum = 0.f, w[NSPLIT];
    #pragma unroll
    for (int s = 0; s < NSPLIT; ++s) { w[s] = ll[s] * exp2f(mm[s] - M); wsum += w[s]; }
    float rinv = 1.0f / wsum;
    #pragma unroll
    for (int s = 0; s < NSPLIT; ++s) w[s] *= rinv;
    float accv[8];
    #pragma unroll
    for (int e = 0; e < 8; ++e) accv[e] = 0.f;
    #pragma unroll
    for (int s = 0; s < NSPLIT; ++s) {
      h16x8 ys = *(const h16x8*)(yP + ((size_t)s * SB + bn) * OO + q * 8);
      #pragma unroll
      for (int e = 0; e < 8; ++e) accv[e] += w[s] * (float)ys[e];
    }
    u32x4 packed;
    #pragma unroll
    for (int e = 0; e < 4; ++e)
      packed[e] = __builtin_bit_cast(u32,
          __builtin_amdgcn_cvt_pkrtz(accv[2 * e], accv[2 * e + 1]));
    *(u32x4*)&Ys[n][q * 8] = packed;
  }
  __syncthreads();

  f32x4 acc[12];
  #pragma unroll
  for (int cf = 0; cf < 12; ++cf) acc[cf] = (f32x4){0.f, 0.f, 0.f, 0.f};
  #pragma unroll
  for (int ks = 0; ks < 3; ++ks) {
    h16x8 yb = *(const h16x8*)&Ys[wv * 16 + l15][ks * 32 + lg * 8];
    #pragma unroll
    for (int cf = 0; cf < 12; ++cf) {
      h16x8 wa = *(const h16x8*)&Wws[cf * 16 + l15][ks * 32 + lg * 8];
      acc[cf] = __builtin_amdgcn_mfma_f32_16x16x32_f16(wa, yb, acc[cf], 0, 0, 0);
    }
  }
  #pragma unroll
  for (int cf = 0; cf < 12; ++cf) {
    #pragma unroll
    for (int r = 0; r < 4; ++r) {
      int c = cf * 16 + lg * 4 + r;
      size_t off = ((size_t)(b * CC + c)) * NN + n0 + wv * 16 + l15;
      out[off] = acc[cf][r] + x[off] + Wb[c];
    }
  }
}

extern "C" void kernel_launch(void* const* d_in, const int* in_sizes, int n_in,
                              void* d_out, int out_size, void* d_ws, size_t ws_size,
                              hipStream_t stream) {
  const float* x    = (const float*)d_in[0];
  const float* g_w  = (const float*)d_in[1];
  const float* g_b  = (const float*)d_in[2];
  const float* th_w = (const float*)d_in[3];
  const float* th_b = (const float*)d_in[4];
  const float* ph_w = (const float*)d_in[5];
  const float* ph_b = (const float*)d_in[6];
  const float* W_w  = (const float*)d_in[7];
  const float* W_b  = (const float*)d_in[8];
  float* out = (float*)d_out;

  char* ws = (char*)d_ws;
  const size_t projB = (size_t)NB * NN * OO * sizeof(u16);   // 6.29 MB
  u16* QB   = (u16*)ws;
  u16* KA   = (u16*)(ws + projB);
  u16* VA   = (u16*)(ws + 2 * projB);
  u16* yP   = (u16*)(ws + 3 * projB);                        // NSPLIT * projB
  float* ml = (float*)(ws + (3 + NSPLIT) * projB);           // 1.05 MB

  dim3 gproj(64, NB);
  hipLaunchKernelGGL(proj_kernel, gproj, dim3(256), 0, stream,
                     x, g_w, g_b, th_w, th_b, ph_w, ph_b, QB, KA, VA);
  dim3 gattn(NB, 32, NSPLIT);
  hipLaunchKernelGGL(attn_kernel, gattn, dim3(128), 0, stream, QB, KA, VA, yP, ml);
  dim3 gout(64, NB);
  hipLaunchKernelGGL(outproj_kernel, gout, dim3(256), 0, stream, x, W_w, W_b, yP, ml, out);
}

// Round 11
// 97.680 us; speedup vs baseline: 1.3179x; 1.0017x over previous
//
#include <hip/hip_runtime.h>

typedef unsigned short u16;
typedef unsigned int u32;
typedef float f32x4 __attribute__((ext_vector_type(4)));
typedef float f32x16 __attribute__((ext_vector_type(16)));
typedef _Float16 h16x8 __attribute__((ext_vector_type(8)));
typedef u32 u32x4 __attribute__((ext_vector_type(4)));
typedef u32 u32x2 __attribute__((ext_vector_type(2)));
typedef u16 u16x4 __attribute__((ext_vector_type(4)));

#define NB 8
#define CC 192
#define OO 96
#define NN 4096
#define NSPLIT 4
#define XPAD 200   // proj LDS row pad
#define LOG2E 1.4426950408889634f

static __device__ __forceinline__ u16 f2h(float f) {
  _Float16 h = (_Float16)f;
  return __builtin_bit_cast(u16, h);
}
static __device__ __forceinline__ void gl_lds16(const u16* g, u16* l) {
  __builtin_amdgcn_global_load_lds(
      (const __attribute__((address_space(1))) void*)g,
      (__attribute__((address_space(3))) void*)l, 16, 0, 0);
}
// raw v_exp_f32: D = 2^S (1 instr; libm exp2f lowers to ~5)
static __device__ __forceinline__ float exp2_raw(float x) {
  float r;
  asm("v_exp_f32 %0, %1" : "=v"(r) : "v"(x));
  return r;
}
// ret0 = [a.lanes0-31 | b.lanes0-31], ret1 = [a.lanes32-63 | b.lanes32-63]
static __device__ __forceinline__ void plane_swap(u32& a, u32& b) {
  u32x2 r = __builtin_amdgcn_permlane32_swap(a, b, false, false);
  a = r[0]; b = r[1];
}
static __device__ __forceinline__ float half_combine_max(float x) {
  u32 a = __builtin_bit_cast(u32, x), b = a;
  plane_swap(a, b);
  return fmaxf(__builtin_bit_cast(float, a), __builtin_bit_cast(float, b));
}
static __device__ __forceinline__ float half_combine_sum(float x) {
  u32 a = __builtin_bit_cast(u32, x), b = a;
  plane_swap(a, b);
  return __builtin_bit_cast(float, a) + __builtin_bit_cast(float, b);
}
static __device__ __forceinline__ float max3f(float a, float b, float c) {
  return fmaxf(fmaxf(a, b), c);   // clang fuses to v_max3_f32
}

// ---------------- Kernel 1: theta/phi/g projections as fp16 MFMA GEMMs ----------------
// Outputs in MFMA-fragment-preswizzled layouts (32x32x16 frags). Theta side is
// pre-scaled by log2(e) so attention can use native exp2.
__global__ __launch_bounds__(256) void proj_kernel(
    const float* __restrict__ x,
    const float* __restrict__ g_w, const float* __restrict__ g_b,
    const float* __restrict__ th_w, const float* __restrict__ th_b,
    const float* __restrict__ ph_w, const float* __restrict__ ph_b,
    u16* __restrict__ QB, u16* __restrict__ KA, u16* __restrict__ VA)
{
  __shared__ __align__(16) u16 Xs[64][XPAD];
  __shared__ __align__(16) u16 Ws[96][XPAD];
  const int b = blockIdx.y, n0 = blockIdx.x * 64, tid = threadIdx.x;
  const int lane = tid & 63, wv = tid >> 6, l15 = lane & 15, lg = lane >> 4;

  #pragma unroll
  for (int it = 0; it < 12; ++it) {
    int idx = tid + it * 256;
    int c = idx >> 4, q = idx & 15;
    float4 v = *(const float4*)(x + ((size_t)(b * CC + c)) * NN + n0 + q * 4);
    Xs[q * 4 + 0][c] = f2h(v.x); Xs[q * 4 + 1][c] = f2h(v.y);
    Xs[q * 4 + 2][c] = f2h(v.z); Xs[q * 4 + 3][c] = f2h(v.w);
  }

  for (int p = 0; p < 3; ++p) {
    const float* w    = (p == 0) ? th_w : (p == 1) ? ph_w : g_w;
    const float* bias = (p == 0) ? th_b : (p == 1) ? ph_b : g_b;
    const float scale = (p == 0) ? LOG2E : 1.0f;
    __syncthreads();
    #pragma unroll
    for (int it = 0; it < 18; ++it) {
      int idx = tid + it * 256;
      int r = idx / 48, q = idx % 48;
      float4 v = *(const float4*)(w + r * CC + q * 4);
      u16x4 hh; hh[0] = f2h(v.x * scale); hh[1] = f2h(v.y * scale);
      hh[2] = f2h(v.z * scale); hh[3] = f2h(v.w * scale);
      *(u16x4*)&Ws[r][q * 4] = hh;
    }
    __syncthreads();

    f32x4 acc[6];
    #pragma unroll
    for (int of = 0; of < 6; ++of) acc[of] = (f32x4){0.f, 0.f, 0.f, 0.f};
    #pragma unroll
    for (int ks = 0; ks < 6; ++ks) {
      h16x8 xa = *(const h16x8*)&Xs[wv * 16 + l15][ks * 32 + lg * 8];
      #pragma unroll
      for (int of = 0; of < 6; ++of) {
        h16x8 wf = *(const h16x8*)&Ws[of * 16 + l15][ks * 32 + lg * 8];
        if (p < 2) acc[of] = __builtin_amdgcn_mfma_f32_16x16x32_f16(xa, wf, acc[of], 0, 0, 0);
        else       acc[of] = __builtin_amdgcn_mfma_f32_16x16x32_f16(wf, xa, acc[of], 0, 0, 0);
      }
    }

    if (p < 2) {   // C[n][o] -> QB / KA (A/B-frag preswizzle)
      u16* dst = (p == 0) ? QB : KA;
      #pragma unroll
      for (int of = 0; of < 6; ++of) {
        int o = of * 16 + l15;
        float bo = bias[o] * scale;
        int kch = of * 2 + (l15 >> 3);
        #pragma unroll
        for (int r = 0; r < 4; ++r) {
          int n = n0 + wv * 16 + lg * 4 + r;
          int idx = (b * 128 + (n >> 5)) * 3072 + (kch * 32 + (n & 31)) * 8 + (o & 7);
          dst[idx] = f2h(acc[of][r] + bo);
        }
      }
    } else {       // C[o][m] -> VA (V^T A-frag preswizzle)
      #pragma unroll
      for (int of = 0; of < 6; ++of) {
        #pragma unroll
        for (int r = 0; r < 4; ++r) {
          int o = of * 16 + lg * 4 + r;
          int m = n0 + wv * 16 + l15;
          int idx = (b * 256 + (m >> 4)) * 1536 +
                    (((o >> 5) * 2 + ((m >> 3) & 1)) * 32 + (o & 31)) * 8 + (m & 7);
          VA[idx] = f2h(acc[of][r] + bias[o]);
        }
      }
    }
  }
}

// ---------------- attention helpers ----------------
static __device__ __forceinline__ void qk_pair(
    const u16* kc, const h16x8* qfA, const h16x8* qfB, int h, int l31,
    f32x16& SA, f32x16& SB)
{
  #pragma unroll
  for (int i = 0; i < 16; ++i) { SA[i] = 0.f; SB[i] = 0.f; }
  #pragma unroll
  for (int ks = 0; ks < 6; ++ks) {
    h16x8 kf = *(const h16x8*)(kc + ((ks * 2 + h) * 32 + l31) * 8);
    SA = __builtin_amdgcn_mfma_f32_32x32x16_f16(kf, qfA[ks], SA, 0, 0, 0);
    SB = __builtin_amdgcn_mfma_f32_32x32x16_f16(kf, qfB[ks], SB, 0, 0, 0);
  }
}

static __device__ __forceinline__ void sm_pair(
    f32x16 SA, f32x16 SB,
    float& mA, float& lA, f32x16* accA,
    float& mB, float& lB, f32x16* accB,
    h16x8* pfA, h16x8* pfB)
{
  float a0 = max3f(SA[0], SA[1], SA[2]),  a1 = max3f(SA[3], SA[4], SA[5]);
  float a2 = max3f(SA[6], SA[7], SA[8]),  a3 = max3f(SA[9], SA[10], SA[11]);
  float a4 = max3f(SA[12], SA[13], SA[14]);
  float pmaxA = half_combine_max(fmaxf(max3f(a0, a1, a2), max3f(a3, a4, SA[15])));
  float b0 = max3f(SB[0], SB[1], SB[2]),  b1 = max3f(SB[3], SB[4], SB[5]);
  float b2 = max3f(SB[6], SB[7], SB[8]),  b3 = max3f(SB[9], SB[10], SB[11]);
  float b4 = max3f(SB[12], SB[13], SB[14]);
  float pmaxB = half_combine_max(fmaxf(max3f(b0, b1, b2), max3f(b3, b4, SB[15])));
  // single merged defer-max branch (8 nats = 11.54 bits)
  if (__ballot((pmaxA > mA + 11.5416f) || (pmaxB > mB + 11.5416f))) {
    float mnA = fmaxf(mA, pmaxA), scA = exp2_raw(mA - mnA);
    float mnB = fmaxf(mB, pmaxB), scB = exp2_raw(mB - mnB);
    mA = mnA; lA *= scA;
    mB = mnB; lB *= scB;
    #pragma unroll
    for (int ob = 0; ob < 3; ++ob)
      #pragma unroll
      for (int i = 0; i < 16; ++i) { accA[ob][i] *= scA; accB[ob][i] *= scB; }
  }
  #pragma unroll
  for (int i = 0; i < 16; ++i) { SA[i] = exp2_raw(SA[i] - mA); SB[i] = exp2_raw(SB[i] - mB); }
  u32 pkA[8], pkB[8];
  #pragma unroll
  for (int i = 0; i < 8; ++i) {
    pkA[i] = __builtin_bit_cast(u32, __builtin_amdgcn_cvt_pkrtz(SA[2 * i], SA[2 * i + 1]));
    pkB[i] = __builtin_bit_cast(u32, __builtin_amdgcn_cvt_pkrtz(SB[2 * i], SB[2 * i + 1]));
  }
  #pragma unroll
  for (int st = 8; st >= 1; st >>= 1)
    #pragma unroll
    for (int i = 0; i < 8; ++i)
      if (i < st) { SA[i] += SA[i + st]; SB[i] += SB[i + st]; }
  lA += half_combine_sum(SA[0]);
  lB += half_combine_sum(SB[0]);
  plane_swap(pkA[0], pkA[2]); plane_swap(pkA[1], pkA[3]);
  plane_swap(pkA[4], pkA[6]); plane_swap(pkA[5], pkA[7]);
  plane_swap(pkB[0], pkB[2]); plane_swap(pkB[1], pkB[3]);
  plane_swap(pkB[4], pkB[6]); plane_swap(pkB[5], pkB[7]);
  u32x4 a0v = {pkA[0], pkA[1], pkA[2], pkA[3]}, a1v = {pkA[4], pkA[5], pkA[6], pkA[7]};
  u32x4 b0v = {pkB[0], pkB[1], pkB[2], pkB[3]}, b1v = {pkB[4], pkB[5], pkB[6], pkB[7]};
  pfA[0] = __builtin_bit_cast(h16x8, a0v); pfA[1] = __builtin_bit_cast(h16x8, a1v);
  pfB[0] = __builtin_bit_cast(h16x8, b0v); pfB[1] = __builtin_bit_cast(h16x8, b1v);
}

static __device__ __forceinline__ void pv_pair(
    const u16* vc, const h16x8* pfA, const h16x8* pfB, int h, int l31,
    f32x16* accA, f32x16* accB)
{
  #pragma unroll
  for (int s2 = 0; s2 < 2; ++s2) {
    #pragma unroll
    for (int ob = 0; ob < 3; ++ob) {
      h16x8 vf = *(const h16x8*)(vc + (((s2 * 3 + ob) * 2 + h) * 32 + l31) * 8);
      accA[ob] = __builtin_amdgcn_mfma_f32_32x32x16_f16(vf, pfA[s2], accA[ob], 0, 0, 0);
      accB[ob] = __builtin_amdgcn_mfma_f32_32x32x16_f16(vf, pfB[s2], accB[ob], 0, 0, 0);
    }
  }
}

// ---------------- Kernel 2: flash attention core (nq=2, pipelined phases) ----------------
// 2 waves x 2 q-chunks (64 q/wave). Single-buffer LDS (24 KB) -> 4 blocks/CU.
// Tile body: QK(0) QK(1) SM(0) PV(0) SM(1) PV(1) -- softmax VALU co-scheduled
// with independent MFMAs of the neighbouring phase (T15 structure).
__global__ __launch_bounds__(128, 2) void attn_kernel(
    const u16* __restrict__ QB, const u16* __restrict__ KA,
    const u16* __restrict__ VA, u16* __restrict__ yP, float* __restrict__ ml)
{
  __shared__ __align__(16) u16 Ks[6144];
  __shared__ __align__(16) u16 Vs[6144];
  const int b   = blockIdx.x;           // XCD-swizzle: id%8 == batch
  const int qt  = blockIdx.y;           // 0..31
  const int sp  = blockIdx.z;           // 0..NSPLIT-1
  const int tid = threadIdx.x;          // 0..127
  const int lane = tid & 63;
  const int wv  = tid >> 6;             // 0..1
  const int l31 = lane & 31;
  const int h   = lane >> 5;

  const int t_start = 16 * sp;
  const int t_end   = 16 * (sp + 1);

  const int ncA = qt * 4 + wv * 2;
  const int ncB = ncA + 1;
  const u16* qbA = QB + (size_t)(b * 128 + ncA) * 3072;
  const u16* qbB = QB + (size_t)(b * 128 + ncB) * 3072;
  h16x8 qfA[6], qfB[6];
  #pragma unroll
  for (int ks = 0; ks < 6; ++ks) {
    qfA[ks] = *(const h16x8*)(qbA + ((ks * 2 + h) * 32 + l31) * 8);
    qfB[ks] = *(const h16x8*)(qbB + ((ks * 2 + h) * 32 + l31) * 8);
  }

  const u16* gk = KA + (size_t)b * (128 * 3072) + (size_t)t_start * 6144;
  const u16* gv = VA + (size_t)b * (256 * 1536) + (size_t)t_start * 6144;

  f32x16 accA[3], accB[3];
  #pragma unroll
  for (int ob = 0; ob < 3; ++ob)
    #pragma unroll
    for (int i = 0; i < 16; ++i) { accA[ob][i] = 0.f; accB[ob][i] = 0.f; }
  float mA = -3.0e38f, lA = 0.f;   // log2-domain running max/sum
  float mB = -3.0e38f, lB = 0.f;

  for (int t = t_start; t < t_end; ++t) {
    // stage tile: K 12288 B + V 12288 B; 128 thr x 16 B x 6 iters each
    #pragma unroll
    for (int i = 0; i < 6; ++i) gl_lds16(gk + tid * 8 + i * 1024, &Ks[tid * 8 + i * 1024]);
    #pragma unroll
    for (int i = 0; i < 6; ++i) gl_lds16(gv + tid * 8 + i * 1024, &Vs[tid * 8 + i * 1024]);
    gk += 6144; gv += 6144;
    asm volatile("s_waitcnt vmcnt(0)" ::: "memory");
    __builtin_amdgcn_s_barrier();
    __builtin_amdgcn_sched_barrier(0);

    f32x16 SA0, SB0, SA1, SB1;
    h16x8 pfA[2], pfB[2];
    // Phase 1: both QK chunk-pairs (4 independent MFMA chains)
    qk_pair(&Ks[0],    qfA, qfB, h, l31, SA0, SB0);
    qk_pair(&Ks[3072], qfA, qfB, h, l31, SA1, SB1);
    // Phase 2: SM(0), then PV(0) -- scheduler fills SM VALU into MFMA slots
    sm_pair(SA0, SB0, mA, lA, accA, mB, lB, accB, pfA, pfB);
    pv_pair(&Vs[0], pfA, pfB, h, l31, accA, accB);
    // Phase 3: SM(1) co-scheduled with PV(0) drain, then PV(1)
    sm_pair(SA1, SB1, mA, lA, accA, mB, lB, accB, pfA, pfB);
    pv_pair(&Vs[3072], pfA, pfB, h, l31, accA, accB);

    __builtin_amdgcn_s_barrier();   // all waves done reading before next stage
  }

  // epilogue: normalized partials + (m,l) per row (log2-domain m)
  #pragma unroll
  for (int qq = 0; qq < 2; ++qq) {
    const f32x16* acc = qq ? accB : accA;
    float mR = qq ? mB : mA, lR = qq ? lB : lA;
    float inv = 1.0f / lR;
    int nglob = (qq ? ncB : ncA) * 32 + l31;
    u16* yp = yP + (((size_t)sp * NB + b) * NN + nglob) * OO;
    #pragma unroll
    for (int ob = 0; ob < 3; ++ob) {
      #pragma unroll
      for (int rq = 0; rq < 4; ++rq) {
        int o0 = ob * 32 + rq * 8 + h * 4;
        u32 w0 = __builtin_bit_cast(u32,
            __builtin_amdgcn_cvt_pkrtz(acc[ob][rq * 4 + 0] * inv, acc[ob][rq * 4 + 1] * inv));
        u32 w1 = __builtin_bit_cast(u32,
            __builtin_amdgcn_cvt_pkrtz(acc[ob][rq * 4 + 2] * inv, acc[ob][rq * 4 + 3] * inv));
        uint2 pr; pr.x = w0; pr.y = w1;
        *(uint2*)&yp[o0] = pr;
      }
    }
    if (h == 0) {
      float2 v2; v2.x = mR; v2.y = lR;
      *(float2*)&ml[(((size_t)sp * NB + b) * NN + nglob) * 2] = v2;
    }
  }
}

// ---------------- Kernel 3: merge partials + W projection + residual ----------------
#define YPAD 104
__global__ __launch_bounds__(256) void outproj_kernel(
    const float* __restrict__ x, const float* __restrict__ Ww,
    const float* __restrict__ Wb, const u16* __restrict__ yP,
    const float* __restrict__ ml, float* __restrict__ out)
{
  __shared__ __align__(16) u16 Wws[CC][YPAD];
  __shared__ __align__(16) u16 Ys[64][YPAD];
  const int b = blockIdx.y, n0 = blockIdx.x * 64, tid = threadIdx.x;
  const int lane = tid & 63, wv = tid >> 6, l15 = lane & 15, lg = lane >> 4;
  const size_t SB = (size_t)NB * NN;

  #pragma unroll
  for (int it = 0; it < 18; ++it) {
    int idx = tid + it * 256;
    int r = idx / 24, q = idx % 24;
    float4 v = *(const float4*)(Ww + r * OO + q * 4);
    u16x4 hh; hh[0] = f2h(v.x); hh[1] = f2h(v.y); hh[2] = f2h(v.z); hh[3] = f2h(v.w);
    *(u16x4*)&Wws[r][q * 4] = hh;
  }
  // stage Ys with in-register NSPLIT-way flash merge
  #pragma unroll
  for (int it = 0; it < 3; ++it) {
    int idx = tid + it * 256;
    int n = idx / 12, q = idx % 12;
    size_t bn = (size_t)b * NN + n0 + n;
    float mm[NSPLIT], ll[NSPLIT];
    float M = -3.0e38f;
    #pragma unroll
    for (int s = 0; s < NSPLIT; ++s) {
      mm[s] = ml[((size_t)s * SB + bn) * 2];
      ll[s] = ml[((size_t)s * SB + bn) * 2 + 1];
      M = fmaxf(M, mm[s]);
    }
    float wsum = 0.f, w[NSPLIT];
    #pragma unroll
    for (int s = 0; s < NSPLIT; ++s) { w[s] = ll[s] * exp2f(mm[s] - M); wsum += w[s]; }
    float rinv = 1.0f / wsum;
    #pragma unroll
    for (int s = 0; s < NSPLIT; ++s) w[s] *= rinv;
    float accv[8];
    #pragma unroll
    for (int e = 0; e < 8; ++e) accv[e] = 0.f;
    #pragma unroll
    for (int s = 0; s < NSPLIT; ++s) {
      h16x8 ys = *(const h16x8*)(yP + ((size_t)s * SB + bn) * OO + q * 8);
      #pragma unroll
      for (int e = 0; e < 8; ++e) accv[e] += w[s] * (float)ys[e];
    }
    u32x4 packed;
    #pragma unroll
    for (int e = 0; e < 4; ++e)
      packed[e] = __builtin_bit_cast(u32,
          __builtin_amdgcn_cvt_pkrtz(accv[2 * e], accv[2 * e + 1]));
    *(u32x4*)&Ys[n][q * 8] = packed;
  }
  __syncthreads();

  f32x4 acc[12];
  #pragma unroll
  for (int cf = 0; cf < 12; ++cf) acc[cf] = (f32x4){0.f, 0.f, 0.f, 0.f};
  #pragma unroll
  for (int ks = 0; ks < 3; ++ks) {
    h16x8 yb = *(const h16x8*)&Ys[wv * 16 + l15][ks * 32 + lg * 8];
    #pragma unroll
    for (int cf = 0; cf < 12; ++cf) {
      h16x8 wa = *(const h16x8*)&Wws[cf * 16 + l15][ks * 32 + lg * 8];
      acc[cf] = __builtin_amdgcn_mfma_f32_16x16x32_f16(wa, yb, acc[cf], 0, 0, 0);
    }
  }
  #pragma unroll
  for (int cf = 0; cf < 12; ++cf) {
    #pragma unroll
    for (int r = 0; r < 4; ++r) {
      int c = cf * 16 + lg * 4 + r;
      size_t off = ((size_t)(b * CC + c)) * NN + n0 + wv * 16 + l15;
      out[off] = acc[cf][r] + x[off] + Wb[c];
    }
  }
}

extern "C" void kernel_launch(void* const* d_in, const int* in_sizes, int n_in,
                              void* d_out, int out_size, void* d_ws, size_t ws_size,
                              hipStream_t stream) {
  const float* x    = (const float*)d_in[0];
  const float* g_w  = (const float*)d_in[1];
  const float* g_b  = (const float*)d_in[2];
  const float* th_w = (const float*)d_in[3];
  const float* th_b = (const float*)d_in[4];
  const float* ph_w = (const float*)d_in[5];
  const float* ph_b = (const float*)d_in[6];
  const float* W_w  = (const float*)d_in[7];
  const float* W_b  = (const float*)d_in[8];
  float* out = (float*)d_out;

  char* ws = (char*)d_ws;
  const size_t projB = (size_t)NB * NN * OO * sizeof(u16);   // 6.29 MB
  u16* QB   = (u16*)ws;
  u16* KA   = (u16*)(ws + projB);
  u16* VA   = (u16*)(ws + 2 * projB);
  u16* yP   = (u16*)(ws + 3 * projB);                        // NSPLIT * projB
  float* ml = (float*)(ws + (3 + NSPLIT) * projB);           // 1.05 MB

  dim3 gproj(64, NB);
  hipLaunchKernelGGL(proj_kernel, gproj, dim3(256), 0, stream,
                     x, g_w, g_b, th_w, th_b, ph_w, ph_b, QB, KA, VA);
  dim3 gattn(NB, 32, NSPLIT);
  hipLaunchKernelGGL(attn_kernel, gattn, dim3(128), 0, stream, QB, KA, VA, yP, ml);
  dim3 gout(64, NB);
  hipLaunchKernelGGL(outproj_kernel, gout, dim3(256), 0, stream, x, W_w, W_b, yP, ml, out);
}